// Round 12
// baseline (1402.238 us; speedup 1.0000x reference)
//
#include <hip/hip_runtime.h>
#include <math.h>

// Problem dims (fixed by the reference)
#define BB 64
#define TT 1024
#define EE 256
#define HH 512
#define OO 32000
#define KDIM 768   // H+E

typedef float f32x2 __attribute__((ext_vector_type(2)));
typedef unsigned long long u64;
typedef unsigned uint4v __attribute__((ext_vector_type(4)));

__device__ __forceinline__ f32x2 mk2(float a, float b) { f32x2 r; r.x = a; r.y = b; return r; }

#if __has_builtin(__builtin_elementwise_fma)
#define FMA2(a, b, c) __builtin_elementwise_fma((a), (b), (c))
#else
__device__ __forceinline__ f32x2 FMA2(f32x2 a, f32x2 b, f32x2 c) {
  c.x = fmaf(a.x, b.x, c.x); c.y = fmaf(a.y, b.y, c.y); return c;
}
#endif

// fast tanh: (e^2x - 1)/(e^2x + 1); v_exp_f32 is 2^x
__device__ __forceinline__ float fast_tanh(float x) {
  float xc = fminf(fmaxf(x, -10.0f), 10.0f);
  float e;
  asm("v_exp_f32 %0, %1" : "=v"(e) : "v"(xc * 2.885390081777927f)); // 2*log2(e)
  float r;
  asm("v_rcp_f32 %0, %1" : "=v"(r) : "v"(e + 1.0f));
  return (e - 1.0f) * r;
}

// paired poll load: 2 tagged {payload,tag} words in one dwordx4 at the IF$
// coherence point (sc0 sc1 = agent-scope encoding, the R4/R6/R8-proven path).
// Each aligned 8-B half is individually single-copy atomic; tags checked
// separately, so a torn 16-B view is harmless.
__device__ __forceinline__ uint4v ld4_ifs(const u64* p) {
  uint4v v;
  asm volatile("global_load_dwordx4 %0, %1, off sc0 sc1\n\ts_waitcnt vmcnt(0)"
               : "=v"(v) : "v"(p) : "memory");
  return v;
}

// Weight tile: 4 j-rows x 24 k-cols = 96 floats/thread, 48 NAMED f32x2
// scalars (no array -> no alloca -> register resident). gi0..gi5 are runtime
// float4-column indices (local role: own-h/e stitched; foreign role: the
// 3 sibling h-slices with own range skipped).
#define FORQ(M, J) M(J,0) M(J,1) M(J,2) M(J,3) M(J,4) M(J,5)
#define FORALL(M) FORQ(M,0) FORQ(M,1) FORQ(M,2) FORQ(M,3)

#define WLOAD(J,Q) float4 v##J##_##Q = wr##J[gi##Q]; \
  f32x2 wa##J##_##Q = mk2(v##J##_##Q.x, v##J##_##Q.y); \
  f32x2 wb##J##_##Q = mk2(v##J##_##Q.z, v##J##_##Q.w);
#define WPIN(J,Q) asm volatile("" : "+v"(wa##J##_##Q), "+v"(wb##J##_##Q));
#define WFMA(J,Q) acc##J = FMA2(wa##J##_##Q, mk2(cc##Q.x, cc##Q.y), acc##J); \
                  acc##J = FMA2(wb##J##_##Q, mk2(cc##Q.z, cc##Q.w), acc##J);
#define CHUNK1(J) WFMA(J,0) WFMA(J,1) WFMA(J,2)
#define CHUNK2(J) WFMA(J,3) WFMA(J,4) WFMA(J,5)

// ---------------------------------------------------------------------------
// Recurrence (R11 structure + early-poll pipelining): 256 blocks, 1024 thr.
// bid -> b = bid&63, s = bid>>6. Block owns rows j in [128s,+128), all 768 k;
// kg 0..15 local {own-h,e}, kg 16..31 foreign.
//   pre-B_mid : waves0-7 local-FMA | 192 pollers: blocking poll of the 384
//               tagged words UNLESS already captured early | e(i+1) prefetch
//   post-B_mid: waves8-15 foreign-FMA | thr0-127 early-reduce local partials
//   post-B1   : thr0-127 final reduce -> publish PRE-ACTIVATION -> own tanh
//               | pollers: ONE bounded probe for tag i+1 (siblings publish
//               concurrently; probe usually hits -> next step's poll vanishes)
//   B2
// Exchange = tagged {u32 tag, f32 preact} parity-double-buffered agent-scope
// words (proven R6/R8/R11). Consumer-side tanh on identical bits.
// ---------------------------------------------------------------------------
__global__ __launch_bounds__(1024, 4) void rnn_kernel(
    const int* __restrict__ x, const float* __restrict__ hidden0,
    const float* __restrict__ emb, const float* __restrict__ Wi,
    const float* __restrict__ bi, float* __restrict__ hid_out,
    u64* __restrict__ psum)
{
  // comb float4 map: [0,32)=own-h, [32,96)=eA, [96,160)=eB, [160,256)=foreign-h
  __shared__ float4 comb4[256];
  __shared__ float4 part4[32 * 32];   // [kg=32][j=128] floats
  __shared__ float part2[128];
  __shared__ int xrow[TT];
  float* comb = (float*)comb4;
  float* part = (float*)part4;

  const int bid = blockIdx.x;
  const int b = bid & 63, s = bid >> 6;
  const int tid = threadIdx.x;
  const int jo = tid & 31;
  const int kg = tid >> 5;            // 0..31
  const bool isLocal = (tid < 512);

  xrow[tid] = x[b * TT + tid];

  // h(0): own 128 -> comb[0..128); foreign 384 -> comb[640..1024)
  if (tid < HH) {
    int j = tid;
    float v = hidden0[b * HH + j];
    int addr = ((j >> 7) == s) ? (j - 128 * s)
                               : (640 + (j < 128 * s ? j : j - 128));
    comb[addr] = v;
  }
  if (tid >= 896 && tid < 960) {      // e(0) -> ebuf0; padding_idx=0 -> zeros
    int t = tid - 896;
    int idx = x[b * TT];
    float4 e0 = make_float4(0.f, 0.f, 0.f, 0.f);
    if (idx != 0) e0 = ((const float4*)emb)[idx * (EE / 4) + t];
    comb4[32 + t] = e0;
  }

  // ---- weight preload: rows 128s+4jo+J, role-dependent f4 columns ----
  const int c4b = 6 * (isLocal ? kg : (kg - 16));
  const int t32s = 32 * s;
  const int c4_0 = c4b + 0, c4_1 = c4b + 1, c4_2 = c4b + 2;
  const int c4_3 = c4b + 3, c4_4 = c4b + 4, c4_5 = c4b + 5;
  // local: c4<32 -> own-h f4 (32s+c4); c4>=32 -> e f4 (96+c4). foreign: skip own.
  const int gi0 = isLocal ? (c4_0 < 32 ? t32s + c4_0 : 96 + c4_0) : (c4_0 + (c4_0 >= t32s ? 32 : 0));
  const int gi1 = isLocal ? (c4_1 < 32 ? t32s + c4_1 : 96 + c4_1) : (c4_1 + (c4_1 >= t32s ? 32 : 0));
  const int gi2 = isLocal ? (c4_2 < 32 ? t32s + c4_2 : 96 + c4_2) : (c4_2 + (c4_2 >= t32s ? 32 : 0));
  const int gi3 = isLocal ? (c4_3 < 32 ? t32s + c4_3 : 96 + c4_3) : (c4_3 + (c4_3 >= t32s ? 32 : 0));
  const int gi4 = isLocal ? (c4_4 < 32 ? t32s + c4_4 : 96 + c4_4) : (c4_4 + (c4_4 >= t32s ? 32 : 0));
  const int gi5 = isLocal ? (c4_5 < 32 ? t32s + c4_5 : 96 + c4_5) : (c4_5 + (c4_5 >= t32s ? 32 : 0));
  const float4* Wi4 = (const float4*)Wi;
  const float4* wr0 = Wi4 + (size_t)(s * 128 + jo * 4 + 0) * (KDIM / 4);
  const float4* wr1 = wr0 + (KDIM / 4);
  const float4* wr2 = wr1 + (KDIM / 4);
  const float4* wr3 = wr2 + (KDIM / 4);
  FORALL(WLOAD)
  FORALL(WPIN)
  const float bias = (tid < 128) ? bi[s * 128 + tid] : 0.0f;
  __syncthreads();   // comb(0), xrow, weights ready

  const int last = TT - 1;
  const int pr = tid - 512;           // poller index, valid 0..191
  // paired foreign indices 2pr, 2pr+1 (shift identical across the pair since
  // 128s is even); psum pair is 16-B aligned
  const int fj0 = (pr >= 0 && pr < 192)
                ? (2 * pr + (2 * pr >= 128 * s ? 128 : 0)) : 0;
  bool early = false;                 // poller: next step's pair already captured

  #pragma unroll 1
  for (int i = 0; i < TT; ++i) {
    const int ebuf = i & 1;
    // ---------------- pre-B_mid ----------------
    if (isLocal) {
      // local FMA over {own-h(i), e(i)}; e sits at +64 f4 when ebuf==1
      const int eo = ebuf * 64;
      const int a0 = c4_0 + (c4_0 >= 32 ? eo : 0);
      const int a1 = c4_1 + (c4_1 >= 32 ? eo : 0);
      const int a2 = c4_2 + (c4_2 >= 32 ? eo : 0);
      const int a3 = c4_3 + (c4_3 >= 32 ? eo : 0);
      const int a4 = c4_4 + (c4_4 >= 32 ? eo : 0);
      const int a5 = c4_5 + (c4_5 >= 32 ? eo : 0);
      f32x2 acc0 = mk2(0.f, 0.f), acc1 = mk2(0.f, 0.f);
      f32x2 acc2 = mk2(0.f, 0.f), acc3 = mk2(0.f, 0.f);
      {
        float4 cc0 = comb4[a0], cc1 = comb4[a1], cc2 = comb4[a2];
        CHUNK1(0) CHUNK1(1) CHUNK1(2) CHUNK1(3)
        float4 cc3 = comb4[a3], cc4 = comb4[a4], cc5 = comb4[a5];
        CHUNK2(0) CHUNK2(1) CHUNK2(2) CHUNK2(3)
      }
      part4[kg * 32 + jo] = make_float4(acc0.x + acc0.y, acc1.x + acc1.y,
                                        acc2.x + acc2.y, acc3.x + acc3.y);
    } else if (pr < 192) {
      if (i > 0 && !early) {
        // blocking poll for the pair (tag i, parity i&1) — straggler path
        const u64* pw = psum + (size_t)(ebuf * BB + b) * HH + fj0;
        const unsigned tgt = (unsigned)i;
        uint4v v = ld4_ifs(pw);
        while (v.y < tgt || v.w < tgt) {
          __builtin_amdgcn_s_sleep(1);
          v = ld4_ifs(pw);
        }
        comb[640 + 2 * pr]     = fast_tanh(__uint_as_float(v.x));
        comb[640 + 2 * pr + 1] = fast_tanh(__uint_as_float(v.z));
      }
      early = false;   // consumed (or step-0 preload); reset for this step's probe
    } else if (pr >= 384 && pr < 448 && i != last) {
      // e(i+1) prefetch into the other e slot (tid 896..959)
      int t = pr - 384;
      int idx = xrow[i + 1];
      float4 e4 = make_float4(0.f, 0.f, 0.f, 0.f);
      if (idx != 0) e4 = ((const float4*)emb)[idx * (EE / 4) + t];
      comb4[32 + (ebuf ^ 1) * 64 + t] = e4;
    }
    __syncthreads();   // B_mid: foreign-h(i) + part[0..15] in LDS

    // ---------------- post-B_mid ----------------
    if (!isLocal) {
      // foreign FMA over comb[640..1024)
      f32x2 acc0 = mk2(0.f, 0.f), acc1 = mk2(0.f, 0.f);
      f32x2 acc2 = mk2(0.f, 0.f), acc3 = mk2(0.f, 0.f);
      {
        float4 cc0 = comb4[160 + c4_0], cc1 = comb4[160 + c4_1], cc2 = comb4[160 + c4_2];
        CHUNK1(0) CHUNK1(1) CHUNK1(2) CHUNK1(3)
        float4 cc3 = comb4[160 + c4_3], cc4 = comb4[160 + c4_4], cc5 = comb4[160 + c4_5];
        CHUNK2(0) CHUNK2(1) CHUNK2(2) CHUNK2(3)
      }
      part4[kg * 32 + jo] = make_float4(acc0.x + acc0.y, acc1.x + acc1.y,
                                        acc2.x + acc2.y, acc3.x + acc3.y);
    } else if (tid < 128) {
      // early-reduce the 16 local partials (runs parallel with foreign FMA)
      float ssum = part[0 * 128 + tid] + part[1 * 128 + tid]
                 + part[2 * 128 + tid] + part[3 * 128 + tid]
                 + part[4 * 128 + tid] + part[5 * 128 + tid]
                 + part[6 * 128 + tid] + part[7 * 128 + tid]
                 + part[8 * 128 + tid] + part[9 * 128 + tid]
                 + part[10 * 128 + tid] + part[11 * 128 + tid]
                 + part[12 * 128 + tid] + part[13 * 128 + tid]
                 + part[14 * 128 + tid] + part[15 * 128 + tid];
      part2[tid] = ssum;
    }
    __syncthreads();   // B1: all 32 partials ready; comb foreign area now dead

    // ---------------- post-B1 ----------------
    if (tid < 128) {
      float ssum = bias + part2[tid]
                 + part[16 * 128 + tid] + part[17 * 128 + tid]
                 + part[18 * 128 + tid] + part[19 * 128 + tid]
                 + part[20 * 128 + tid] + part[21 * 128 + tid]
                 + part[22 * 128 + tid] + part[23 * 128 + tid]
                 + part[24 * 128 + tid] + part[25 * 128 + tid]
                 + part[26 * 128 + tid] + part[27 * 128 + tid]
                 + part[28 * 128 + tid] + part[29 * 128 + tid]
                 + part[30 * 128 + tid] + part[31 * 128 + tid];
      if (i == last) {
        hid_out[b * HH + s * 128 + tid] = fast_tanh(ssum);
      } else {
        // publish PRE-ACTIVATION first (flight starts before tanh)
        u64 pv = ((u64)(unsigned)(i + 1) << 32) | __float_as_uint(ssum);
        __hip_atomic_store(psum + (size_t)(((i + 1) & 1) * BB + b) * HH
                               + (s * 128 + tid),
                           pv, __ATOMIC_RELAXED, __HIP_MEMORY_SCOPE_AGENT);
        comb[tid] = fast_tanh(ssum);   // own-h for step i+1
      }
    } else if (pr >= 0 && pr < 192 && i != last) {
      // ONE bounded probe for next step's pair (tag i+1, parity (i+1)&1).
      // Siblings are publishing tag i+1 right now — probe usually hits.
      // comb foreign area is dead after B1, so the write is safe here.
      const u64* pw = psum + (size_t)((ebuf ^ 1) * BB + b) * HH + fj0;
      const unsigned tgt = (unsigned)(i + 1);
      uint4v v = ld4_ifs(pw);
      if (v.y >= tgt && v.w >= tgt) {
        comb[640 + 2 * pr]     = fast_tanh(__uint_as_float(v.x));
        comb[640 + 2 * pr + 1] = fast_tanh(__uint_as_float(v.z));
        early = true;
      }
    }
    __syncthreads();   // B2: comb own-h(i+1) in place; next step may proceed
  }
}

// ---------------------------------------------------------------------------
// Decoder: out[b][o] = sum_j h[b][j] * W_dec[o][j] + b_dec[o]
// ---------------------------------------------------------------------------
__global__ __launch_bounds__(256) void dec_kernel(
    const float* __restrict__ hid, const float* __restrict__ Wd,
    const float* __restrict__ bd, float* __restrict__ out)
{
  __shared__ float4 hl4[32 * 128];
  const int o  = blockIdx.x * 256 + threadIdx.x;
  const int b0 = blockIdx.y * 32;

  const float4* hid4 = (const float4*)(hid + b0 * HH);
  #pragma unroll
  for (int i = 0; i < 16; ++i) {
    int lin = i * 256 + threadIdx.x;
    hl4[lin] = hid4[lin];
  }
  __syncthreads();

  f32x2 acc[32];
  #pragma unroll
  for (int bb = 0; bb < 32; ++bb) acc[bb] = mk2(0.f, 0.f);

  const float4* W4 = (const float4*)(Wd + (size_t)o * HH);
  for (int j4 = 0; j4 < 128; ++j4) {
    float4 w = W4[j4];
    f32x2 wa = mk2(w.x, w.y), wb = mk2(w.z, w.w);
    #pragma unroll
    for (int bb = 0; bb < 32; ++bb) {
      float4 h = hl4[bb * 128 + j4];
      acc[bb] = FMA2(wa, mk2(h.x, h.y), acc[bb]);
      acc[bb] = FMA2(wb, mk2(h.z, h.w), acc[bb]);
    }
  }

  const float bias = bd[o];
  #pragma unroll
  for (int bb = 0; bb < 32; ++bb)
    out[(size_t)(b0 + bb) * OO + o] = acc[bb].x + acc[bb].y + bias;
}

// ---------------------------------------------------------------------------
extern "C" void kernel_launch(void* const* d_in, const int* in_sizes, int n_in,
                              void* d_out, int out_size, void* d_ws, size_t ws_size,
                              hipStream_t stream) {
  const int*   x    = (const int*)  d_in[0];   // [64][1024] int32
  const float* hid0 = (const float*)d_in[1];   // [64][512]
  const float* emb  = (const float*)d_in[2];   // [32000][256]
  const float* Wi   = (const float*)d_in[3];   // [512][768]
  const float* bi   = (const float*)d_in[4];   // [512]
  const float* Wd   = (const float*)d_in[5];   // [32000][512]
  const float* bd   = (const float*)d_in[6];   // [32000]

  float* out     = (float*)d_out;              // [64][32000]
  float* hid_out = out + (size_t)BB * OO;      // [64][512] final hidden

  u64* psum = (u64*)d_ws;                      // [2][64][512] tagged words

  // zero all tags every launch: graph replays repeat the same tag sequence,
  // so stale tags from the previous replay would alias (capture-legal memset)
  hipMemsetAsync(d_ws, 0, (size_t)2 * BB * HH * sizeof(u64), stream);

  rnn_kernel<<<BB * 4, 1024, 0, stream>>>(x, hid0, emb, Wi, bi, hid_out, psum);
  dec_kernel<<<dim3(OO / 256, BB / 32), 256, 0, stream>>>(hid_out, Wd, bd, out);
}

// Round 14
// 1215.805 us; speedup vs baseline: 1.1533x; 1.1533x over previous
//
#include <hip/hip_runtime.h>
#include <math.h>

// Problem dims (fixed by the reference)
#define BB 64
#define TT 1024
#define EE 256
#define HH 512
#define OO 32000
#define KDIM 768   // H+E

typedef float f32x2 __attribute__((ext_vector_type(2)));
typedef unsigned long long u64;
typedef unsigned uint4v __attribute__((ext_vector_type(4)));

__device__ __forceinline__ f32x2 mk2(float a, float b) { f32x2 r; r.x = a; r.y = b; return r; }

#if __has_builtin(__builtin_elementwise_fma)
#define FMA2(a, b, c) __builtin_elementwise_fma((a), (b), (c))
#else
__device__ __forceinline__ f32x2 FMA2(f32x2 a, f32x2 b, f32x2 c) {
  c.x = fmaf(a.x, b.x, c.x); c.y = fmaf(a.y, b.y, c.y); return c;
}
#endif

// Raw barrier WITHOUT the vmcnt(0) drain __syncthreads would emit.
// All in-loop cross-wave dependencies are LDS-only (comb/part/part2), so
// lgkmcnt(0) + s_barrier is sufficient; psum global stores are allowed to
// stay in flight across the barrier (their visibility is carried by the
// self-validating tag protocol, never by intra-block ordering).
#define BAR() asm volatile("s_waitcnt lgkmcnt(0)\n\ts_barrier" ::: "memory")

// fast tanh: (e^2x - 1)/(e^2x + 1); v_exp_f32 is 2^x
__device__ __forceinline__ float fast_tanh(float x) {
  float xc = fminf(fmaxf(x, -10.0f), 10.0f);
  float e;
  asm("v_exp_f32 %0, %1" : "=v"(e) : "v"(xc * 2.885390081777927f)); // 2*log2(e)
  float r;
  asm("v_rcp_f32 %0, %1" : "=v"(r) : "v"(e + 1.0f));
  return (e - 1.0f) * r;
}

// paired poll load: 2 tagged {payload,tag} words in one dwordx4 at the IF$
// coherence point (sc0 sc1 = agent-scope encoding — the ONLY safe cross-block
// visibility primitive on gfx950; sc0-only polls hit stale L1 forever, the
// R5/R13 hang mode). Each aligned 8-B half is individually single-copy
// atomic; tags checked separately, so a torn 16-B view is harmless.
__device__ __forceinline__ uint4v ld4_ifs(const u64* p) {
  uint4v v;
  asm volatile("global_load_dwordx4 %0, %1, off sc0 sc1\n\ts_waitcnt vmcnt(0)"
               : "=v"(v) : "v"(p) : "memory");
  return v;
}

// Weight tile: 4 j-rows x 24 k-cols = 96 floats/thread, 48 NAMED f32x2
// scalars (no array -> no alloca -> register resident). gi0..gi5 are runtime
// float4-column indices (local role: own-h/e stitched; foreign role: the
// 3 sibling h-slices with own range skipped).
#define FORQ(M, J) M(J,0) M(J,1) M(J,2) M(J,3) M(J,4) M(J,5)
#define FORALL(M) FORQ(M,0) FORQ(M,1) FORQ(M,2) FORQ(M,3)

#define WLOAD(J,Q) float4 v##J##_##Q = wr##J[gi##Q]; \
  f32x2 wa##J##_##Q = mk2(v##J##_##Q.x, v##J##_##Q.y); \
  f32x2 wb##J##_##Q = mk2(v##J##_##Q.z, v##J##_##Q.w);
#define WPIN(J,Q) asm volatile("" : "+v"(wa##J##_##Q), "+v"(wb##J##_##Q));
#define WFMA(J,Q) acc##J = FMA2(wa##J##_##Q, mk2(cc##Q.x, cc##Q.y), acc##J); \
                  acc##J = FMA2(wb##J##_##Q, mk2(cc##Q.z, cc##Q.w), acc##J);
#define CHUNK1(J) WFMA(J,0) WFMA(J,1) WFMA(J,2)
#define CHUNK2(J) WFMA(J,3) WFMA(J,4) WFMA(J,5)

// ---------------------------------------------------------------------------
// Recurrence (R11 structure + drain-free barriers): 256 blocks, 1024 thr.
// bid -> b = bid&63, s = bid>>6. Block owns rows j in [128s,+128), all 768 k;
// kg 0..15 local {own-h,e}, kg 16..31 foreign.
//   pre-B_mid : waves0-7 local-FMA | 192 pollers x4-poll 384 tagged words
//               (s_sleep retry) | thr896-959 e(i+1) prefetch
//   post-B_mid: waves8-15 foreign-FMA | thr0-127 early-reduce local partials
//   post-B1   : thr0-127 final reduce -> publish PRE-ACTIVATION -> own tanh
//   B2 (lgkm-only: the psum store flies across, landing during the
//       siblings' next poll window instead of stalling this block)
// Exchange = tagged {u32 tag, f32 preact} parity-double-buffered agent-scope
// words (proven R6/R8/R11). Consumer-side tanh on identical bits.
// ---------------------------------------------------------------------------
__global__ __launch_bounds__(1024, 4) void rnn_kernel(
    const int* __restrict__ x, const float* __restrict__ hidden0,
    const float* __restrict__ emb, const float* __restrict__ Wi,
    const float* __restrict__ bi, float* __restrict__ hid_out,
    u64* __restrict__ psum)
{
  // comb float4 map: [0,32)=own-h, [32,96)=eA, [96,160)=eB, [160,256)=foreign-h
  __shared__ float4 comb4[256];
  __shared__ float4 part4[32 * 32];   // [kg=32][j=128] floats
  __shared__ float part2[128];
  __shared__ int xrow[TT];
  float* comb = (float*)comb4;
  float* part = (float*)part4;

  const int bid = blockIdx.x;
  const int b = bid & 63, s = bid >> 6;
  const int tid = threadIdx.x;
  const int jo = tid & 31;
  const int kg = tid >> 5;            // 0..31
  const bool isLocal = (tid < 512);

  xrow[tid] = x[b * TT + tid];

  // h(0): own 128 -> comb[0..128); foreign 384 -> comb[640..1024)
  if (tid < HH) {
    int j = tid;
    float v = hidden0[b * HH + j];
    int addr = ((j >> 7) == s) ? (j - 128 * s)
                               : (640 + (j < 128 * s ? j : j - 128));
    comb[addr] = v;
  }
  if (tid >= 896 && tid < 960) {      // e(0) -> ebuf0; padding_idx=0 -> zeros
    int t = tid - 896;
    int idx = x[b * TT];
    float4 e0 = make_float4(0.f, 0.f, 0.f, 0.f);
    if (idx != 0) e0 = ((const float4*)emb)[idx * (EE / 4) + t];
    comb4[32 + t] = e0;
  }

  // ---- weight preload: rows 128s+4jo+J, role-dependent f4 columns ----
  const int c4b = 6 * (isLocal ? kg : (kg - 16));
  const int t32s = 32 * s;
  const int c4_0 = c4b + 0, c4_1 = c4b + 1, c4_2 = c4b + 2;
  const int c4_3 = c4b + 3, c4_4 = c4b + 4, c4_5 = c4b + 5;
  // local: c4<32 -> own-h f4 (32s+c4); c4>=32 -> e f4 (96+c4). foreign: skip own.
  const int gi0 = isLocal ? (c4_0 < 32 ? t32s + c4_0 : 96 + c4_0) : (c4_0 + (c4_0 >= t32s ? 32 : 0));
  const int gi1 = isLocal ? (c4_1 < 32 ? t32s + c4_1 : 96 + c4_1) : (c4_1 + (c4_1 >= t32s ? 32 : 0));
  const int gi2 = isLocal ? (c4_2 < 32 ? t32s + c4_2 : 96 + c4_2) : (c4_2 + (c4_2 >= t32s ? 32 : 0));
  const int gi3 = isLocal ? (c4_3 < 32 ? t32s + c4_3 : 96 + c4_3) : (c4_3 + (c4_3 >= t32s ? 32 : 0));
  const int gi4 = isLocal ? (c4_4 < 32 ? t32s + c4_4 : 96 + c4_4) : (c4_4 + (c4_4 >= t32s ? 32 : 0));
  const int gi5 = isLocal ? (c4_5 < 32 ? t32s + c4_5 : 96 + c4_5) : (c4_5 + (c4_5 >= t32s ? 32 : 0));
  const float4* Wi4 = (const float4*)Wi;
  const float4* wr0 = Wi4 + (size_t)(s * 128 + jo * 4 + 0) * (KDIM / 4);
  const float4* wr1 = wr0 + (KDIM / 4);
  const float4* wr2 = wr1 + (KDIM / 4);
  const float4* wr3 = wr2 + (KDIM / 4);
  FORALL(WLOAD)
  FORALL(WPIN)
  const float bias = (tid < 128) ? bi[s * 128 + tid] : 0.0f;
  __syncthreads();   // one full-drain barrier: comb(0), xrow, weights ready

  const int last = TT - 1;
  const int pr = tid - 512;           // poller index, valid 0..191
  // paired foreign indices 2pr, 2pr+1 (shift identical across the pair since
  // 128s is even); psum pair is 16-B aligned
  const int fj0 = (pr >= 0 && pr < 192)
                ? (2 * pr + (2 * pr >= 128 * s ? 128 : 0)) : 0;

  #pragma unroll 1
  for (int i = 0; i < TT; ++i) {
    const int ebuf = i & 1;
    // ---------------- pre-B_mid ----------------
    if (isLocal) {
      // local FMA over {own-h(i), e(i)}; e sits at +64 f4 when ebuf==1
      const int eo = ebuf * 64;
      const int a0 = c4_0 + (c4_0 >= 32 ? eo : 0);
      const int a1 = c4_1 + (c4_1 >= 32 ? eo : 0);
      const int a2 = c4_2 + (c4_2 >= 32 ? eo : 0);
      const int a3 = c4_3 + (c4_3 >= 32 ? eo : 0);
      const int a4 = c4_4 + (c4_4 >= 32 ? eo : 0);
      const int a5 = c4_5 + (c4_5 >= 32 ? eo : 0);
      f32x2 acc0 = mk2(0.f, 0.f), acc1 = mk2(0.f, 0.f);
      f32x2 acc2 = mk2(0.f, 0.f), acc3 = mk2(0.f, 0.f);
      {
        float4 cc0 = comb4[a0], cc1 = comb4[a1], cc2 = comb4[a2];
        CHUNK1(0) CHUNK1(1) CHUNK1(2) CHUNK1(3)
        float4 cc3 = comb4[a3], cc4 = comb4[a4], cc5 = comb4[a5];
        CHUNK2(0) CHUNK2(1) CHUNK2(2) CHUNK2(3)
      }
      part4[kg * 32 + jo] = make_float4(acc0.x + acc0.y, acc1.x + acc1.y,
                                        acc2.x + acc2.y, acc3.x + acc3.y);
    } else if (pr < 192) {
      if (i > 0) {
        // poll a PAIR of tagged foreign words (pre-activation, tag i)
        const u64* pw = psum + (size_t)(ebuf * BB + b) * HH + fj0;
        const unsigned tgt = (unsigned)i;
        uint4v v = ld4_ifs(pw);
        while (v.y < tgt || v.w < tgt) {
          __builtin_amdgcn_s_sleep(1);
          v = ld4_ifs(pw);
        }
        // consumer-side tanh (identical bits -> identical h everywhere)
        comb[640 + 2 * pr]     = fast_tanh(__uint_as_float(v.x));
        comb[640 + 2 * pr + 1] = fast_tanh(__uint_as_float(v.z));
      }
    } else if (pr >= 384 && pr < 448 && i != last) {
      // e(i+1) prefetch into the other e slot (tid 896..959)
      int t = pr - 384;
      int idx = xrow[i + 1];
      float4 e4 = make_float4(0.f, 0.f, 0.f, 0.f);
      if (idx != 0) e4 = ((const float4*)emb)[idx * (EE / 4) + t];
      comb4[32 + (ebuf ^ 1) * 64 + t] = e4;
    }
    BAR();   // B_mid: foreign-h(i) + part[0..15] in LDS (lgkm-only drain)

    // ---------------- post-B_mid ----------------
    if (!isLocal) {
      // foreign FMA over comb[640..1024)
      f32x2 acc0 = mk2(0.f, 0.f), acc1 = mk2(0.f, 0.f);
      f32x2 acc2 = mk2(0.f, 0.f), acc3 = mk2(0.f, 0.f);
      {
        float4 cc0 = comb4[160 + c4_0], cc1 = comb4[160 + c4_1], cc2 = comb4[160 + c4_2];
        CHUNK1(0) CHUNK1(1) CHUNK1(2) CHUNK1(3)
        float4 cc3 = comb4[160 + c4_3], cc4 = comb4[160 + c4_4], cc5 = comb4[160 + c4_5];
        CHUNK2(0) CHUNK2(1) CHUNK2(2) CHUNK2(3)
      }
      part4[kg * 32 + jo] = make_float4(acc0.x + acc0.y, acc1.x + acc1.y,
                                        acc2.x + acc2.y, acc3.x + acc3.y);
    } else if (tid < 128) {
      // early-reduce the 16 local partials (runs parallel with foreign FMA)
      float ssum = part[0 * 128 + tid] + part[1 * 128 + tid]
                 + part[2 * 128 + tid] + part[3 * 128 + tid]
                 + part[4 * 128 + tid] + part[5 * 128 + tid]
                 + part[6 * 128 + tid] + part[7 * 128 + tid]
                 + part[8 * 128 + tid] + part[9 * 128 + tid]
                 + part[10 * 128 + tid] + part[11 * 128 + tid]
                 + part[12 * 128 + tid] + part[13 * 128 + tid]
                 + part[14 * 128 + tid] + part[15 * 128 + tid];
      part2[tid] = ssum;
    }
    BAR();   // B1: all 32 partials ready (lgkm-only drain)

    // ---------------- post-B1 ----------------
    if (tid < 128) {
      float ssum = bias + part2[tid]
                 + part[16 * 128 + tid] + part[17 * 128 + tid]
                 + part[18 * 128 + tid] + part[19 * 128 + tid]
                 + part[20 * 128 + tid] + part[21 * 128 + tid]
                 + part[22 * 128 + tid] + part[23 * 128 + tid]
                 + part[24 * 128 + tid] + part[25 * 128 + tid]
                 + part[26 * 128 + tid] + part[27 * 128 + tid]
                 + part[28 * 128 + tid] + part[29 * 128 + tid]
                 + part[30 * 128 + tid] + part[31 * 128 + tid];
      if (i == last) {
        hid_out[b * HH + s * 128 + tid] = fast_tanh(ssum);
      } else {
        // publish PRE-ACTIVATION first (flight starts before tanh, and the
        // store is NOT drained at B2 — it lands during the siblings' poll)
        u64 pv = ((u64)(unsigned)(i + 1) << 32) | __float_as_uint(ssum);
        __hip_atomic_store(psum + (size_t)(((i + 1) & 1) * BB + b) * HH
                               + (s * 128 + tid),
                           pv, __ATOMIC_RELAXED, __HIP_MEMORY_SCOPE_AGENT);
        comb[tid] = fast_tanh(ssum);   // own-h for step i+1
      }
    }
    BAR();   // B2: comb own-h(i+1) in place (lgkm-only drain)
  }
}

// ---------------------------------------------------------------------------
// Decoder: out[b][o] = sum_j h[b][j] * W_dec[o][j] + b_dec[o]
// ---------------------------------------------------------------------------
__global__ __launch_bounds__(256) void dec_kernel(
    const float* __restrict__ hid, const float* __restrict__ Wd,
    const float* __restrict__ bd, float* __restrict__ out)
{
  __shared__ float4 hl4[32 * 128];
  const int o  = blockIdx.x * 256 + threadIdx.x;
  const int b0 = blockIdx.y * 32;

  const float4* hid4 = (const float4*)(hid + b0 * HH);
  #pragma unroll
  for (int i = 0; i < 16; ++i) {
    int lin = i * 256 + threadIdx.x;
    hl4[lin] = hid4[lin];
  }
  __syncthreads();

  f32x2 acc[32];
  #pragma unroll
  for (int bb = 0; bb < 32; ++bb) acc[bb] = mk2(0.f, 0.f);

  const float4* W4 = (const float4*)(Wd + (size_t)o * HH);
  for (int j4 = 0; j4 < 128; ++j4) {
    float4 w = W4[j4];
    f32x2 wa = mk2(w.x, w.y), wb = mk2(w.z, w.w);
    #pragma unroll
    for (int bb = 0; bb < 32; ++bb) {
      float4 h = hl4[bb * 128 + j4];
      acc[bb] = FMA2(wa, mk2(h.x, h.y), acc[bb]);
      acc[bb] = FMA2(wb, mk2(h.z, h.w), acc[bb]);
    }
  }

  const float bias = bd[o];
  #pragma unroll
  for (int bb = 0; bb < 32; ++bb)
    out[(size_t)(b0 + bb) * OO + o] = acc[bb].x + acc[bb].y + bias;
}

// ---------------------------------------------------------------------------
extern "C" void kernel_launch(void* const* d_in, const int* in_sizes, int n_in,
                              void* d_out, int out_size, void* d_ws, size_t ws_size,
                              hipStream_t stream) {
  const int*   x    = (const int*)  d_in[0];   // [64][1024] int32
  const float* hid0 = (const float*)d_in[1];   // [64][512]
  const float* emb  = (const float*)d_in[2];   // [32000][256]
  const float* Wi   = (const float*)d_in[3];   // [512][768]
  const float* bi   = (const float*)d_in[4];   // [512]
  const float* Wd   = (const float*)d_in[5];   // [32000][512]
  const float* bd   = (const float*)d_in[6];   // [32000]

  float* out     = (float*)d_out;              // [64][32000]
  float* hid_out = out + (size_t)BB * OO;      // [64][512] final hidden

  u64* psum = (u64*)d_ws;                      // [2][64][512] tagged words

  // zero all tags every launch: graph replays repeat the same tag sequence,
  // so stale tags from the previous replay would alias (capture-legal memset)
  hipMemsetAsync(d_ws, 0, (size_t)2 * BB * HH * sizeof(u64), stream);

  rnn_kernel<<<BB * 4, 1024, 0, stream>>>(x, hid0, emb, Wi, bi, hid_out, psum);
  dec_kernel<<<dim3(OO / 256, BB / 32), 256, 0, stream>>>(hid_out, Wd, bd, out);
}